// Round 2
// baseline (2464.044 us; speedup 1.0000x reference)
//
#include <hip/hip_runtime.h>
#include <math.h>
#include <float.h>

// Autoformer working-condition decomposition block, f32 correctness-first.
// B=8, L=4096, D=512, H=4, E=128, TOP_K=8.
#define LSEQ 4096
#define DM   512
#define NB   8

__device__ __forceinline__ int rev12(int x) { return (int)(__brev((unsigned)x) >> 20); }

// ---------------------------------------------------------------------------
// Generic GEMM: Y[b,l,n] (= or +=) sum_k A[b,(l+shift)%L,k] * W[n*ldw + k*wstride]
//               (+ bias[n]) (+ resid[b,l,n])
// TRANS_OUT: write Y[b,n,l] instead (for FFT-friendly q^T / k^T layout).
// 64x64 tile, BK=16, 256 threads, 4x4 microtile.
// ---------------------------------------------------------------------------
template<bool TRANS_OUT>
__global__ void __launch_bounds__(256)
gemm_k(const float* __restrict__ A, const float* __restrict__ W,
       const float* __restrict__ bias, const float* __restrict__ resid,
       float* __restrict__ Y, int ldw, int wstride, int shift, int accum)
{
    const int b  = blockIdx.z;
    const int l0 = blockIdx.x * 64;
    const int n0 = blockIdx.y * 64;
    const int tid = (int)threadIdx.x;
    const int tx = tid & 15, ty = tid >> 4;

    __shared__ float As[16][68];   // [k][m], pad 68 keeps float4 alignment + clean banks
    __shared__ float Ws[16][68];   // [k][n]

    float acc[4][4] = {};

    const float* Ab = A + (size_t)b * LSEQ * DM;
    const int mload = tid >> 2;          // 0..63
    const int kload = (tid & 3) << 2;    // 0,4,8,12

    for (int k0 = 0; k0 < DM; k0 += 16) {
        int row = (l0 + mload + shift) & (LSEQ - 1);   // circular within batch
        float4 av = *(const float4*)(Ab + (size_t)row * DM + (k0 + kload));
        float4 wv;
        const float* wsrc = W + (size_t)(n0 + mload) * ldw + (size_t)(k0 + kload) * wstride;
        if (wstride == 1) {
            wv = *(const float4*)wsrc;
        } else {
            wv.x = wsrc[0]; wv.y = wsrc[wstride]; wv.z = wsrc[2*wstride]; wv.w = wsrc[3*wstride];
        }
        As[kload+0][mload] = av.x; As[kload+1][mload] = av.y;
        As[kload+2][mload] = av.z; As[kload+3][mload] = av.w;
        Ws[kload+0][mload] = wv.x; Ws[kload+1][mload] = wv.y;
        Ws[kload+2][mload] = wv.z; Ws[kload+3][mload] = wv.w;
        __syncthreads();
        #pragma unroll
        for (int kk = 0; kk < 16; kk++) {
            float4 a4 = *(const float4*)&As[kk][ty*4];
            float4 b4 = *(const float4*)&Ws[kk][tx*4];
            float aa[4] = {a4.x, a4.y, a4.z, a4.w};
            float bb[4] = {b4.x, b4.y, b4.z, b4.w};
            #pragma unroll
            for (int i = 0; i < 4; i++)
                #pragma unroll
                for (int j = 0; j < 4; j++)
                    acc[i][j] += aa[i] * bb[j];
        }
        __syncthreads();
    }

    if constexpr (!TRANS_OUT) {
        #pragma unroll
        for (int i = 0; i < 4; i++) {
            int m = l0 + ty*4 + i;
            size_t base = ((size_t)b * LSEQ + m) * DM + n0 + tx*4;
            float vals[4];
            #pragma unroll
            for (int j = 0; j < 4; j++) {
                float val = acc[i][j];
                if (bias) val += bias[n0 + tx*4 + j];
                vals[j] = val;
            }
            if (resid) {
                float4 r4 = *(const float4*)(resid + base);
                vals[0] += r4.x; vals[1] += r4.y; vals[2] += r4.z; vals[3] += r4.w;
            }
            if (accum) {
                float4 y4 = *(const float4*)(Y + base);
                vals[0] += y4.x; vals[1] += y4.y; vals[2] += y4.z; vals[3] += y4.w;
            }
            float4 o = { vals[0], vals[1], vals[2], vals[3] };
            *(float4*)(Y + base) = o;
        }
    } else {
        __shared__ float tile[64][65];
        #pragma unroll
        for (int i = 0; i < 4; i++)
            #pragma unroll
            for (int j = 0; j < 4; j++)
                tile[ty*4+i][tx*4+j] = acc[i][j];
        __syncthreads();
        for (int idx = tid; idx < 4096; idx += 256) {
            int nl = idx >> 6, ml = idx & 63;
            float val = tile[ml][nl];
            int n = n0 + nl;
            if (bias) val += bias[n];
            Y[((size_t)b * DM + n) * LSEQ + (l0 + ml)] = val;   // coalesced along l
        }
    }
}

// ---------------------------------------------------------------------------
// Forward correlation spectrum. One block = (batch b, 8 channels).
// Packed complex FFT z = q + i*k, DIF (natural in -> bit-rev out), so LDS
// loads/stores stay linear (no bit-reversal permutation, no 32-way conflicts).
// Extract Q*conj(K) in the bit-reversed domain, atomically accumulate into
// Shat[b][p] (bit-rev-indexed spectrum). Pairs with the DIT inverse below.
// ---------------------------------------------------------------------------
__global__ void __launch_bounds__(256)
fft_corr_k(const float* __restrict__ qt, const float* __restrict__ kt,
           float* __restrict__ S)
{
    __shared__ float zr[LSEQ], zi[LSEQ];
    __shared__ float twc[LSEQ/2], tws[LSEQ/2];
    const int cg  = blockIdx.x;   // 0..63 channel-groups of 8
    const int b   = blockIdx.y;
    const int tid = (int)threadIdx.x;

    for (int j = tid; j < LSEQ/2; j += 256) {
        float ang = -2.0f * 3.14159265358979323846f * (float)j / (float)LSEQ;
        float s, c;
        sincosf(ang, &s, &c);
        twc[j] = c; tws[j] = s;
    }

    float Sr[16] = {}, Si[16] = {};

    for (int ci = 0; ci < 8; ci++) {
        const int ch = cg * 8 + ci;
        const float* qp = qt + ((size_t)b * DM + ch) * LSEQ;
        const float* kp = kt + ((size_t)b * DM + ch) * LSEQ;
        __syncthreads();   // also covers twiddle table on first iteration
        for (int j = tid; j < LSEQ; j += 256) { zr[j] = qp[j]; zi[j] = kp[j]; }
        __syncthreads();
        // DIF stages: half = 2048 .. 1
        for (int s = 11; s >= 0; s--) {
            int half = 1 << s;
            for (int bf = tid; bf < LSEQ/2; bf += 256) {
                int grp = bf >> s;
                int pos = bf & (half - 1);
                int i1  = (grp << (s + 1)) + pos;
                int i2  = i1 + half;
                int tdx = pos << (11 - s);
                float wc = twc[tdx], wsn = tws[tdx];
                float ur = zr[i1], ui = zi[i1];
                float vr = zr[i2], vi = zi[i2];
                zr[i1] = ur + vr;  zi[i1] = ui + vi;
                float dr = ur - vr, di = ui - vi;
                zr[i2] = wc * dr - wsn * di;
                zi[i2] = wc * di + wsn * dr;
            }
            __syncthreads();
        }
        // z1 = Z[w] at p, z2 = Z[N-w] at rev(N-rev(p)).
        // Q = (z1 + conj(z2))/2, K = -i(z1 - conj(z2))/2, S += Q*conj(K).
        #pragma unroll
        for (int j = 0; j < 16; j++) {
            int p  = tid + j * 256;
            int om = rev12(p);
            int pp = rev12((LSEQ - om) & (LSEQ - 1));
            float z1r = zr[p],  z1i = zi[p];
            float z2r = zr[pp], z2i = zi[pp];
            float Qr = 0.5f * (z1r + z2r);
            float Qi = 0.5f * (z1i - z2i);
            float Kr = 0.5f * (z1i + z2i);
            float Ki = 0.5f * (z2r - z1r);
            Sr[j] += Qr * Kr + Qi * Ki;
            Si[j] += Qi * Kr - Qr * Ki;
        }
    }
    float* Sb = S + (size_t)b * LSEQ * 2;
    #pragma unroll
    for (int j = 0; j < 16; j++) {
        int p = tid + j * 256;
        atomicAdd(&Sb[2*p],   Sr[j]);
        atomicAdd(&Sb[2*p+1], Si[j]);
    }
}

// ---------------------------------------------------------------------------
// Inverse FFT per batch (input already bit-reversed => DIT, natural output),
// then top-8 delays + softmax weights. mean_value = Re(IFFT(S)) / (L*D).
// ---------------------------------------------------------------------------
__global__ void __launch_bounds__(256)
ifft_topk_k(const float* __restrict__ S, float* __restrict__ wbuf, int* __restrict__ dbuf)
{
    __shared__ float zr[LSEQ], zi[LSEQ];
    __shared__ float twc[LSEQ/2], tws[LSEQ/2];
    __shared__ float rv[256];
    __shared__ int   ri[256];
    __shared__ float topv[8];
    __shared__ int   topi[8];
    const int b   = blockIdx.x;
    const int tid = (int)threadIdx.x;

    for (int j = tid; j < LSEQ/2; j += 256) {
        float ang = -2.0f * 3.14159265358979323846f * (float)j / (float)LSEQ;
        float s, c;
        sincosf(ang, &s, &c);
        twc[j] = c; tws[j] = s;
    }
    const float* Sb = S + (size_t)b * LSEQ * 2;
    // IFFT(S) = conj(FFT(conj(S)))/N; S Hermitian => result real, take Re.
    for (int j = tid; j < LSEQ; j += 256) { zr[j] = Sb[2*j]; zi[j] = -Sb[2*j+1]; }
    __syncthreads();
    for (int s = 0; s < 12; s++) {   // DIT stages
        int half = 1 << s;
        for (int bf = tid; bf < LSEQ/2; bf += 256) {
            int grp = bf >> s;
            int pos = bf & (half - 1);
            int i1  = (grp << (s + 1)) + pos;
            int i2  = i1 + half;
            int tdx = pos << (11 - s);
            float wc = twc[tdx], wsn = tws[tdx];
            float vr = zr[i2], vi = zi[i2];
            float tr = wc * vr - wsn * vi;
            float ti = wc * vi + wsn * vr;
            float ur = zr[i1], ui = zi[i1];
            zr[i1] = ur + tr;  zi[i1] = ui + ti;
            zr[i2] = ur - tr;  zi[i2] = ui - ti;
        }
        __syncthreads();
    }
    const float scale = 1.0f / ((float)LSEQ * (float)DM);
    for (int j = tid; j < LSEQ; j += 256) zr[j] *= scale;   // mean_value in zr
    __syncthreads();

    for (int it = 0; it < 8; it++) {
        float best = -FLT_MAX; int bidx = 0;
        for (int j = tid; j < LSEQ; j += 256) {
            float vv = zr[j];
            if (vv > best) { best = vv; bidx = j; }   // strict > keeps lowest idx on ties
        }
        rv[tid] = best; ri[tid] = bidx;
        __syncthreads();
        for (int off = 128; off > 0; off >>= 1) {
            if (tid < off) {
                float ov = rv[tid+off]; int oi = ri[tid+off];
                if (ov > rv[tid] || (ov == rv[tid] && oi < ri[tid])) { rv[tid] = ov; ri[tid] = oi; }
            }
            __syncthreads();
        }
        if (tid == 0) {
            topv[it] = rv[0]; topi[it] = ri[0];
            zr[ri[0]] = -FLT_MAX;
        }
        __syncthreads();
    }
    if (tid == 0) {
        float m = topv[0];
        float e[8], sum = 0.f;
        #pragma unroll
        for (int i = 0; i < 8; i++) { e[i] = expf(topv[i] - m); sum += e[i]; }
        #pragma unroll
        for (int i = 0; i < 8; i++) { wbuf[b*8+i] = e[i] / sum; dbuf[b*8+i] = topi[i]; }
    }
}

// ---------------------------------------------------------------------------
// agg[b,l,c] = sum_i w[b,i] * v[b,(l+delay_i)%L,c]. One block per (b,l) row.
// ---------------------------------------------------------------------------
__global__ void __launch_bounds__(256)
gather_k(const float* __restrict__ v, const float* __restrict__ wbuf,
         const int* __restrict__ dbuf, float* __restrict__ agg)
{
    const int l   = blockIdx.x;
    const int b   = blockIdx.y;
    const int tid = (int)threadIdx.x;
    __shared__ float w[8];
    __shared__ int   dd[8];
    if (tid < 8) { w[tid] = wbuf[b*8+tid]; dd[tid] = dbuf[b*8+tid]; }
    __syncthreads();
    const float* vb = v + (size_t)b * LSEQ * DM;
    int c = tid * 2;
    float2 acc = {0.f, 0.f};
    #pragma unroll
    for (int i = 0; i < 8; i++) {
        int src = (l + dd[i]) & (LSEQ - 1);
        float2 val = *(const float2*)(vb + (size_t)src * DM + c);
        acc.x += w[i] * val.x;
        acc.y += w[i] * val.y;
    }
    *(float2*)(agg + ((size_t)b * LSEQ + l) * DM + c) = acc;
}

// ---------------------------------------------------------------------------
extern "C" void kernel_launch(void* const* d_in, const int* in_sizes, int n_in,
                              void* d_out, int out_size, void* d_ws, size_t ws_size,
                              hipStream_t stream)
{
    const float* x_s = (const float*)d_in[0];
    const float* x_w = (const float*)d_in[1];
    const float* Wq  = (const float*)d_in[2];
    const float* bq  = (const float*)d_in[3];
    const float* Wk  = (const float*)d_in[4];
    const float* bk  = (const float*)d_in[5];
    const float* Wv  = (const float*)d_in[6];
    const float* bv  = (const float*)d_in[7];
    const float* Wo  = (const float*)d_in[8];
    const float* bo  = (const float*)d_in[9];
    const float* Wc  = (const float*)d_in[10];   // (out=512, in=512, k=3)

    float* out_s = (float*)d_out;                        // x_s_out [B,L,D]
    float* out_w = out_s + (size_t)NB * LSEQ * DM;       // x_w_out [B,L,D]

    const size_t NBLD = (size_t)NB * LSEQ * DM;          // 16,777,216 floats
    float* ws   = (float*)d_ws;
    float* qt   = ws;                 // [B,D,L] q^T
    float* kt   = ws + NBLD;          // [B,D,L] k^T
    // Workspace budget: prefer v in ws (3 big buffers ~202 MB); if ws is too
    // small, park v in the out_w half of d_out (dead until the conv GEMMs,
    // and v is fully consumed by gather_k before those run). Decision depends
    // only on ws_size -> identical work every call (graph-capture safe).
    const size_t need3 = (3 * NBLD + (size_t)NB * LSEQ * 2 + 256) * sizeof(float);
    float* vbuf = (ws_size >= need3) ? (ws + 2 * NBLD) : out_w;
    float* Sbuf = (ws_size >= need3) ? (ws + 3 * NBLD) : (ws + 2 * NBLD);
    float* agg  = qt;                 // reuse: qt dead after fft_corr_k
    float* wbuf = Sbuf + (size_t)NB * LSEQ * 2;
    int*   dbuf = (int*)(wbuf + NB * 8);

    dim3 ggrid(LSEQ/64, DM/64, NB);

    // q = x_w@Wq.T+bq (transposed out), k = x_s@Wk.T+bk (transposed), v natural
    gemm_k<true ><<<ggrid, 256, 0, stream>>>(x_w, Wq, bq, nullptr, qt,   DM, 1, 0, 0);
    gemm_k<true ><<<ggrid, 256, 0, stream>>>(x_s, Wk, bk, nullptr, kt,   DM, 1, 0, 0);
    gemm_k<false><<<ggrid, 256, 0, stream>>>(x_s, Wv, bv, nullptr, vbuf, DM, 1, 0, 0);

    hipMemsetAsync(Sbuf, 0, (size_t)NB * LSEQ * 2 * sizeof(float), stream);

    fft_corr_k <<<dim3(64, NB), 256, 0, stream>>>(qt, kt, Sbuf);
    ifft_topk_k<<<dim3(NB),     256, 0, stream>>>(Sbuf, wbuf, dbuf);
    gather_k   <<<dim3(LSEQ, NB), 256, 0, stream>>>(vbuf, wbuf, dbuf, agg);

    // x_s_out = x_s + agg@Wo.T + bo
    gemm_k<false><<<ggrid, 256, 0, stream>>>(agg, Wo, bo, x_s, out_s, DM, 1, 0, 0);

    // x_w_out = circular conv1d: 3 shifted accumulating GEMMs, weight stride 3
    gemm_k<false><<<ggrid, 256, 0, stream>>>(x_w, Wc + 0, nullptr, nullptr, out_w, 3*DM, 3, -1, 0);
    gemm_k<false><<<ggrid, 256, 0, stream>>>(x_w, Wc + 1, nullptr, nullptr, out_w, 3*DM, 3,  0, 1);
    gemm_k<false><<<ggrid, 256, 0, stream>>>(x_w, Wc + 2, nullptr, nullptr, out_w, 3*DM, 3,  1, 1);
}

// Round 3
// 1265.277 us; speedup vs baseline: 1.9474x; 1.9474x over previous
//
#include <hip/hip_runtime.h>
#include <math.h>
#include <float.h>

// Autoformer block: bf16-MFMA GEMMs (split-precision for q/k), f32 FFT path.
// B=8, L=4096, D=512, H=4, E=128, TOP_K=8.
#define LSEQ 4096
#define DM   512
#define NB   8

typedef __attribute__((ext_vector_type(8))) short bf16x8;
typedef __attribute__((ext_vector_type(4))) float f32x4;

__device__ __forceinline__ int rev12(int x) { return (int)(__brev((unsigned)x) >> 20); }

__device__ __forceinline__ short f2bf(float x) {
    union { float f; unsigned u; } v; v.f = x;
    unsigned r = (v.u + 0x7FFFu + ((v.u >> 16) & 1u)) >> 16;
    return (short)r;
}
__device__ __forceinline__ float bf2f(short h) {
    union { unsigned u; float f; } v; v.u = ((unsigned)(unsigned short)h) << 16;
    return v.f;
}

// ---------------------------------------------------------------------------
// MFMA GEMM: Y[b,m,n] = sum_k A[b,rowmap(m,k),k'] * W(n,k)  (+bias) (+resid)
//  SPLIT: A,W split into bf16 hi+lo, 3 MFMAs (hi*hi + hi*lo + lo*hi) ~ f32.
//  TRANS: write Y[b,n,m] (q^T/k^T for FFT) via per-wave LDS transpose.
//  CONV : K=1536; k=(tap*512+kin); A row circular-shifted by tap-1;
//         W element = W[n*1536 + kin*3 + tap]  (Wconv is [out][in][3]).
// 128x128 tile, BK=32, 256 threads (4 waves, 2x2), 4x4 frags of 16x16x32.
// Reg-staged f32->bf16 conversion (no bf16 input copies needed).
// ---------------------------------------------------------------------------
template<int SPLIT, int TRANS, int CONV>
__global__ void __launch_bounds__(256)
mm_k(const float* __restrict__ A, const float* __restrict__ W,
     const float* __restrict__ bias, const float* __restrict__ resid,
     float* __restrict__ Y)
{
    constexpr int K = CONV ? 3 * DM : DM;
    __shared__ __align__(16) char pool[32768];   // Ah|Wh|Al|Wl tiles, 8KB each

    const int bz = blockIdx.z;
    const int m0 = blockIdx.x * 128;
    const int n0 = blockIdx.y * 128;
    const int tid  = (int)threadIdx.x;
    const int lane = tid & 63, wave = tid >> 6;
    const int wm = wave & 1, wn = wave >> 1;
    const int fr = lane & 15, fq = lane >> 4;

    const float* Ab = A + (size_t)bz * LSEQ * DM;

    const int srow = tid >> 1;        // 0..127 (tile row)
    const int skh  = tid & 1;         // k half (16 elems each)

    float af[16], wf[16];

    auto load_regs = [&](int k0) {
        int t  = CONV ? (k0 >> 9) : 0;
        int ar = m0 + srow;
        if (CONV) ar = (ar + t - 1) & (LSEQ - 1);
        const float* ap = Ab + (size_t)ar * DM + (CONV ? (k0 & (DM - 1)) : k0) + skh * 16;
        #pragma unroll
        for (int g = 0; g < 4; g++) {
            float4 v4 = *(const float4*)(ap + g * 4);
            af[g*4+0] = v4.x; af[g*4+1] = v4.y; af[g*4+2] = v4.z; af[g*4+3] = v4.w;
        }
        if (!CONV) {
            const float* wp = W + (size_t)(n0 + srow) * DM + k0 + skh * 16;
            #pragma unroll
            for (int g = 0; g < 4; g++) {
                float4 v4 = *(const float4*)(wp + g * 4);
                wf[g*4+0] = v4.x; wf[g*4+1] = v4.y; wf[g*4+2] = v4.z; wf[g*4+3] = v4.w;
            }
        } else {
            const float* wp = W + (size_t)(n0 + srow) * (3 * DM)
                                + (size_t)((k0 & (DM - 1)) + skh * 16) * 3 + t;
            #pragma unroll
            for (int e = 0; e < 16; e++) wf[e] = wp[e * 3];
        }
    };

    auto stage = [&]() {
        bf16x8 vh[2], wh[2], vl[2], wl[2];
        #pragma unroll
        for (int h = 0; h < 2; h++)
            #pragma unroll
            for (int e = 0; e < 8; e++) {
                float xa = af[h*8+e], xw = wf[h*8+e];
                short ha = f2bf(xa), hw = f2bf(xw);
                vh[h][e] = ha; wh[h][e] = hw;
                if (SPLIT) {
                    vl[h][e] = f2bf(xa - bf2f(ha));
                    wl[h][e] = f2bf(xw - bf2f(hw));
                }
            }
        const int off = srow * 64 + skh * 32;   // [row][k] bf16, 64B rows
        *(bf16x8*)(pool + off)             = vh[0];
        *(bf16x8*)(pool + off + 16)        = vh[1];
        *(bf16x8*)(pool + 8192 + off)      = wh[0];
        *(bf16x8*)(pool + 8192 + off + 16) = wh[1];
        if (SPLIT) {
            *(bf16x8*)(pool + 16384 + off)      = vl[0];
            *(bf16x8*)(pool + 16384 + off + 16) = vl[1];
            *(bf16x8*)(pool + 24576 + off)      = wl[0];
            *(bf16x8*)(pool + 24576 + off + 16) = wl[1];
        }
    };

    f32x4 acc[4][4];
    #pragma unroll
    for (int i = 0; i < 4; i++)
        #pragma unroll
        for (int j = 0; j < 4; j++)
            acc[i][j] = (f32x4){0.f, 0.f, 0.f, 0.f};

    const int abase = (wm * 64 + fr) * 64 + fq * 16;   // byte offsets
    const int bbase = (wn * 64 + fr) * 64 + fq * 16;

    load_regs(0);
    for (int k0 = 0; k0 < K; k0 += 32) {
        __syncthreads();                 // prev readers done -> safe to overwrite
        stage();
        if (k0 + 32 < K) load_regs(k0 + 32);   // prefetch overlaps MFMA phase
        __syncthreads();                 // tile visible
        bf16x8 a[4], b[4];
        #pragma unroll
        for (int i = 0; i < 4; i++) a[i] = *(const bf16x8*)(pool + abase + i * 1024);
        #pragma unroll
        for (int j = 0; j < 4; j++) b[j] = *(const bf16x8*)(pool + 8192 + bbase + j * 1024);
        if (SPLIT) {
            bf16x8 a2[4], b2[4];
            #pragma unroll
            for (int i = 0; i < 4; i++) a2[i] = *(const bf16x8*)(pool + 16384 + abase + i * 1024);
            #pragma unroll
            for (int j = 0; j < 4; j++) b2[j] = *(const bf16x8*)(pool + 24576 + bbase + j * 1024);
            #pragma unroll
            for (int i = 0; i < 4; i++)
                #pragma unroll
                for (int j = 0; j < 4; j++) {
                    acc[i][j] = __builtin_amdgcn_mfma_f32_16x16x32_bf16(a[i],  b[j],  acc[i][j], 0, 0, 0);
                    acc[i][j] = __builtin_amdgcn_mfma_f32_16x16x32_bf16(a[i],  b2[j], acc[i][j], 0, 0, 0);
                    acc[i][j] = __builtin_amdgcn_mfma_f32_16x16x32_bf16(a2[i], b[j],  acc[i][j], 0, 0, 0);
                }
        } else {
            #pragma unroll
            for (int i = 0; i < 4; i++)
                #pragma unroll
                for (int j = 0; j < 4; j++)
                    acc[i][j] = __builtin_amdgcn_mfma_f32_16x16x32_bf16(a[i], b[j], acc[i][j], 0, 0, 0);
        }
    }

    if constexpr (!TRANS) {
        // C/D layout (m89): col = lane&15, row = (lane>>4)*4 + reg
        #pragma unroll
        for (int i = 0; i < 4; i++)
            #pragma unroll
            for (int r = 0; r < 4; r++) {
                int m = m0 + wm * 64 + i * 16 + fq * 4 + r;
                size_t rowb = ((size_t)bz * LSEQ + m) * DM;
                #pragma unroll
                for (int j = 0; j < 4; j++) {
                    int n = n0 + wn * 64 + j * 16 + fr;
                    float val = acc[i][j][r];
                    if (bias)  val += bias[n];
                    if (resid) val += resid[rowb + n];
                    Y[rowb + n] = val;
                }
            }
    } else {
        // per-wave LDS transpose -> Y[b,n,m] with m contiguous (coalesced)
        __syncthreads();                 // all waves done reading tiles
        float* sl = (float*)pool + wave * (64 * 17);
        #pragma unroll
        for (int i = 0; i < 4; i++) {
            #pragma unroll
            for (int j = 0; j < 4; j++) {
                int nn = j * 16 + fr;
                float bv = bias ? bias[n0 + wn * 64 + nn] : 0.f;
                #pragma unroll
                for (int r = 0; r < 4; r++)
                    sl[nn * 17 + fq * 4 + r] = acc[i][j][r] + bv;
            }
            // same-wave DS ops execute in order; cross-lane read below is safe
            const float* sr = sl + lane * 17;
            int n = n0 + wn * 64 + lane;
            float* dst = Y + ((size_t)bz * DM + n) * LSEQ + m0 + wm * 64 + i * 16;
            #pragma unroll
            for (int g = 0; g < 4; g++) {
                float4 o = { sr[g*4+0], sr[g*4+1], sr[g*4+2], sr[g*4+3] };
                *(float4*)(dst + g * 4) = o;
            }
        }
    }
}

// ---------------------------------------------------------------------------
// Forward correlation spectrum (unchanged from passing round).
// ---------------------------------------------------------------------------
__global__ void __launch_bounds__(256)
fft_corr_k(const float* __restrict__ qt, const float* __restrict__ kt,
           float* __restrict__ S)
{
    __shared__ float zr[LSEQ], zi[LSEQ];
    __shared__ float twc[LSEQ/2], tws[LSEQ/2];
    const int cg  = blockIdx.x;
    const int b   = blockIdx.y;
    const int tid = (int)threadIdx.x;

    for (int j = tid; j < LSEQ/2; j += 256) {
        float ang = -2.0f * 3.14159265358979323846f * (float)j / (float)LSEQ;
        float s, c;
        sincosf(ang, &s, &c);
        twc[j] = c; tws[j] = s;
    }

    float Sr[16] = {}, Si[16] = {};

    for (int ci = 0; ci < 8; ci++) {
        const int ch = cg * 8 + ci;
        const float* qp = qt + ((size_t)b * DM + ch) * LSEQ;
        const float* kp = kt + ((size_t)b * DM + ch) * LSEQ;
        __syncthreads();
        for (int j = tid; j < LSEQ; j += 256) { zr[j] = qp[j]; zi[j] = kp[j]; }
        __syncthreads();
        for (int s = 11; s >= 0; s--) {
            int half = 1 << s;
            for (int bf = tid; bf < LSEQ/2; bf += 256) {
                int grp = bf >> s;
                int pos = bf & (half - 1);
                int i1  = (grp << (s + 1)) + pos;
                int i2  = i1 + half;
                int tdx = pos << (11 - s);
                float wc = twc[tdx], wsn = tws[tdx];
                float ur = zr[i1], ui = zi[i1];
                float vr = zr[i2], vi = zi[i2];
                zr[i1] = ur + vr;  zi[i1] = ui + vi;
                float dr = ur - vr, di = ui - vi;
                zr[i2] = wc * dr - wsn * di;
                zi[i2] = wc * di + wsn * dr;
            }
            __syncthreads();
        }
        #pragma unroll
        for (int j = 0; j < 16; j++) {
            int p  = tid + j * 256;
            int om = rev12(p);
            int pp = rev12((LSEQ - om) & (LSEQ - 1));
            float z1r = zr[p],  z1i = zi[p];
            float z2r = zr[pp], z2i = zi[pp];
            float Qr = 0.5f * (z1r + z2r);
            float Qi = 0.5f * (z1i - z2i);
            float Kr = 0.5f * (z1i + z2i);
            float Ki = 0.5f * (z2r - z1r);
            Sr[j] += Qr * Kr + Qi * Ki;
            Si[j] += Qi * Kr - Qr * Ki;
        }
    }
    float* Sb = S + (size_t)b * LSEQ * 2;
    #pragma unroll
    for (int j = 0; j < 16; j++) {
        int p = tid + j * 256;
        atomicAdd(&Sb[2*p],   Sr[j]);
        atomicAdd(&Sb[2*p+1], Si[j]);
    }
}

// ---------------------------------------------------------------------------
__global__ void __launch_bounds__(256)
ifft_topk_k(const float* __restrict__ S, float* __restrict__ wbuf, int* __restrict__ dbuf)
{
    __shared__ float zr[LSEQ], zi[LSEQ];
    __shared__ float twc[LSEQ/2], tws[LSEQ/2];
    __shared__ float rv[256];
    __shared__ int   ri[256];
    __shared__ float topv[8];
    __shared__ int   topi[8];
    const int b   = blockIdx.x;
    const int tid = (int)threadIdx.x;

    for (int j = tid; j < LSEQ/2; j += 256) {
        float ang = -2.0f * 3.14159265358979323846f * (float)j / (float)LSEQ;
        float s, c;
        sincosf(ang, &s, &c);
        twc[j] = c; tws[j] = s;
    }
    const float* Sb = S + (size_t)b * LSEQ * 2;
    for (int j = tid; j < LSEQ; j += 256) { zr[j] = Sb[2*j]; zi[j] = -Sb[2*j+1]; }
    __syncthreads();
    for (int s = 0; s < 12; s++) {
        int half = 1 << s;
        for (int bf = tid; bf < LSEQ/2; bf += 256) {
            int grp = bf >> s;
            int pos = bf & (half - 1);
            int i1  = (grp << (s + 1)) + pos;
            int i2  = i1 + half;
            int tdx = pos << (11 - s);
            float wc = twc[tdx], wsn = tws[tdx];
            float vr = zr[i2], vi = zi[i2];
            float tr = wc * vr - wsn * vi;
            float ti = wc * vi + wsn * vr;
            float ur = zr[i1], ui = zi[i1];
            zr[i1] = ur + tr;  zi[i1] = ui + ti;
            zr[i2] = ur - tr;  zi[i2] = ui - ti;
        }
        __syncthreads();
    }
    const float scale = 1.0f / ((float)LSEQ * (float)DM);
    for (int j = tid; j < LSEQ; j += 256) zr[j] *= scale;
    __syncthreads();

    for (int it = 0; it < 8; it++) {
        float best = -FLT_MAX; int bidx = 0;
        for (int j = tid; j < LSEQ; j += 256) {
            float vv = zr[j];
            if (vv > best) { best = vv; bidx = j; }
        }
        rv[tid] = best; ri[tid] = bidx;
        __syncthreads();
        for (int off = 128; off > 0; off >>= 1) {
            if (tid < off) {
                float ov = rv[tid+off]; int oi = ri[tid+off];
                if (ov > rv[tid] || (ov == rv[tid] && oi < ri[tid])) { rv[tid] = ov; ri[tid] = oi; }
            }
            __syncthreads();
        }
        if (tid == 0) {
            topv[it] = rv[0]; topi[it] = ri[0];
            zr[ri[0]] = -FLT_MAX;
        }
        __syncthreads();
    }
    if (tid == 0) {
        float m = topv[0];
        float e[8], sum = 0.f;
        #pragma unroll
        for (int i = 0; i < 8; i++) { e[i] = expf(topv[i] - m); sum += e[i]; }
        #pragma unroll
        for (int i = 0; i < 8; i++) { wbuf[b*8+i] = e[i] / sum; dbuf[b*8+i] = topi[i]; }
    }
}

// ---------------------------------------------------------------------------
__global__ void __launch_bounds__(256)
gather_k(const float* __restrict__ v, const float* __restrict__ wbuf,
         const int* __restrict__ dbuf, float* __restrict__ agg)
{
    const int l   = blockIdx.x;
    const int b   = blockIdx.y;
    const int tid = (int)threadIdx.x;
    __shared__ float w[8];
    __shared__ int   dd[8];
    if (tid < 8) { w[tid] = wbuf[b*8+tid]; dd[tid] = dbuf[b*8+tid]; }
    __syncthreads();
    const float* vb = v + (size_t)b * LSEQ * DM;
    int c = tid * 2;
    float2 acc = {0.f, 0.f};
    #pragma unroll
    for (int i = 0; i < 8; i++) {
        int src = (l + dd[i]) & (LSEQ - 1);
        float2 val = *(const float2*)(vb + (size_t)src * DM + c);
        acc.x += w[i] * val.x;
        acc.y += w[i] * val.y;
    }
    *(float2*)(agg + ((size_t)b * LSEQ + l) * DM + c) = acc;
}

// ---------------------------------------------------------------------------
extern "C" void kernel_launch(void* const* d_in, const int* in_sizes, int n_in,
                              void* d_out, int out_size, void* d_ws, size_t ws_size,
                              hipStream_t stream)
{
    const float* x_s = (const float*)d_in[0];
    const float* x_w = (const float*)d_in[1];
    const float* Wq  = (const float*)d_in[2];
    const float* bq  = (const float*)d_in[3];
    const float* Wk  = (const float*)d_in[4];
    const float* bk  = (const float*)d_in[5];
    const float* Wv  = (const float*)d_in[6];
    const float* bv  = (const float*)d_in[7];
    const float* Wo  = (const float*)d_in[8];
    const float* bo  = (const float*)d_in[9];
    const float* Wc  = (const float*)d_in[10];   // (out=512, in=512, k=3)

    float* out_s = (float*)d_out;                        // x_s_out [B,L,D]
    float* out_w = out_s + (size_t)NB * LSEQ * DM;       // x_w_out [B,L,D]

    const size_t NBLD = (size_t)NB * LSEQ * DM;          // 16,777,216 floats
    float* ws = (float*)d_ws;
    float* qt = ws;                  // [B,D,L] q^T (f32)
    float* kt = ws + NBLD;           // [B,D,L] k^T (f32)
    const size_t need3 = (3 * NBLD + (size_t)NB * LSEQ * 2 + 256) * sizeof(float);
    float* vbuf = (ws_size >= need3) ? (ws + 2 * NBLD) : out_w;   // v dead before conv writes out_w
    float* Sbuf = (ws_size >= need3) ? (ws + 3 * NBLD) : (ws + 2 * NBLD);
    float* agg  = qt;                // reuse: qt dead after fft_corr_k
    float* wbuf = Sbuf + (size_t)NB * LSEQ * 2;
    int*   dbuf = (int*)(wbuf + NB * 8);

    dim3 mgrid(LSEQ / 128, DM / 128, NB);

    // q^T, k^T: split-precision MFMA (selection-critical); v: plain bf16 MFMA
    mm_k<1,1,0><<<mgrid, 256, 0, stream>>>(x_w, Wq, bq, nullptr, qt);
    mm_k<1,1,0><<<mgrid, 256, 0, stream>>>(x_s, Wk, bk, nullptr, kt);
    mm_k<0,0,0><<<mgrid, 256, 0, stream>>>(x_s, Wv, bv, nullptr, vbuf);

    hipMemsetAsync(Sbuf, 0, (size_t)NB * LSEQ * 2 * sizeof(float), stream);

    fft_corr_k <<<dim3(64, NB),   256, 0, stream>>>(qt, kt, Sbuf);
    ifft_topk_k<<<dim3(NB),       256, 0, stream>>>(Sbuf, wbuf, dbuf);
    gather_k   <<<dim3(LSEQ, NB), 256, 0, stream>>>(vbuf, wbuf, dbuf, agg);

    // x_s_out = x_s + agg@Wo.T + bo
    mm_k<0,0,0><<<mgrid, 256, 0, stream>>>(agg, Wo, bo, x_s, out_s);

    // x_w_out = circular conv1d, fused as one K=1536 GEMM
    mm_k<0,0,1><<<mgrid, 256, 0, stream>>>(x_w, Wc, nullptr, nullptr, out_w);
}

// Round 4
// 940.288 us; speedup vs baseline: 2.6205x; 1.3456x over previous
//
#include <hip/hip_runtime.h>
#include <math.h>
#include <float.h>

// Autoformer block: bf16-MFMA GEMMs (split-precision for q/k), f32 FFT path.
// B=8, L=4096, D=512, H=4, E=128, TOP_K=8.
#define LSEQ 4096
#define DM   512
#define NB   8

typedef __attribute__((ext_vector_type(8))) short bf16x8;
typedef __attribute__((ext_vector_type(4))) float f32x4;

__device__ __forceinline__ int rev12(int x) { return (int)(__brev((unsigned)x) >> 20); }

__device__ __forceinline__ short f2bf(float x) {   // RNE
    union { float f; unsigned u; } v; v.f = x;
    unsigned r = (v.u + 0x7FFFu + ((v.u >> 16) & 1u)) >> 16;
    return (short)r;
}

// ---------------------------------------------------------------------------
// Wconv [out][in][3] -> wt [tap][out][in]  (makes conv-GEMM W loads float4able)
// ---------------------------------------------------------------------------
__global__ void __launch_bounds__(256)
wconv_tr_k(const float* __restrict__ Wc, float* __restrict__ wt)
{
    int idx = blockIdx.x * 256 + (int)threadIdx.x;      // over 512*512 (n,kin)
    float a = Wc[(size_t)idx * 3 + 0];
    float b = Wc[(size_t)idx * 3 + 1];
    float c = Wc[(size_t)idx * 3 + 2];
    wt[0 * (DM*DM) + idx] = a;
    wt[1 * (DM*DM) + idx] = b;
    wt[2 * (DM*DM) + idx] = c;
}

// ---------------------------------------------------------------------------
// MFMA GEMM: Y[b,m,n] = sum_k A[b,rowmap(m,k),k'] * W(n,k)  (+bias) (+resid)
//  SPLIT: A,W split into bf16 hi+lo (truncation split: lo is exact remainder),
//         3 MFMAs (hi*hi + hi*lo + lo*hi) ~ f32 accuracy.
//  TRANS: write Y[b,n,m] (q^T/k^T for FFT) via per-wave LDS transpose.
//  CONV : K=1536; k=(tap*512+kin); A row circular-shifted by tap-1;
//         W = wt[tap][n][kin] (pre-transposed).
// 128x128 tile, BK=32, 256 threads (4 waves 2x2), 4x4 frags of 16x16x32.
// Global loads: 8 lanes/row x consecutive float4 -> full 64B-line use.
// LDS rows 80B (64 data + 16 pad): fragment reads ~2-way bank alias (free).
// ---------------------------------------------------------------------------
template<int SPLIT, int TRANS, int CONV>
__global__ void __launch_bounds__(256)
mm_k(const float* __restrict__ A, const float* __restrict__ W,
     const float* __restrict__ bias, const float* __restrict__ resid,
     float* __restrict__ Y)
{
    constexpr int K    = CONV ? 3 * DM : DM;
    constexpr int RB   = 80;            // LDS bytes per 32-elem bf16 row
    constexpr int TILE = 128 * RB;      // 10240
    constexpr int POOL = SPLIT ? 4 * TILE : 2 * TILE;
    __shared__ __align__(16) char pool[POOL];

    const int bz = blockIdx.z;
    const int m0 = blockIdx.x * 128;
    const int n0 = blockIdx.y * 128;
    const int tid  = (int)threadIdx.x;
    const int lane = tid & 63, wave = tid >> 6;
    const int wm = wave & 1, wn = wave >> 1;
    const int fr = lane & 15, fq = lane >> 4;

    const float* Ab = A + (size_t)bz * LSEQ * DM;

    const int rl0 = (wave << 3) + (lane >> 3);   // row_local base (add 32 per g)
    const int kq  = lane & 7;                    // float4 slot within 32-float slice

    float4 av[4], wv[4];

    auto load_regs = [&](int k0) {
        const int t   = CONV ? (k0 >> 9) : 0;
        const int kin = (CONV ? (k0 & (DM - 1)) : k0) + kq * 4;
        #pragma unroll
        for (int g = 0; g < 4; g++) {
            int rl = rl0 + g * 32;
            int ar = m0 + rl;
            if (CONV) ar = (ar + t - 1) & (LSEQ - 1);
            av[g] = *(const float4*)(Ab + (size_t)ar * DM + kin);
            const float* wp = CONV
                ? (W + (size_t)t * (DM * DM) + (size_t)(n0 + rl) * DM + kin)
                : (W + (size_t)(n0 + rl) * DM + kin);
            wv[g] = *(const float4*)wp;
        }
    };

    auto stage = [&]() {
        #pragma unroll
        for (int g = 0; g < 4; g++) {
            const int off = (rl0 + g * 32) * RB + kq * 8;
            float x[4] = {av[g].x, av[g].y, av[g].z, av[g].w};
            float y[4] = {wv[g].x, wv[g].y, wv[g].z, wv[g].w};
            if (SPLIT) {
                short4 ah, wh, al, wl;
                short* ahp = &ah.x; short* whp = &wh.x;
                short* alp = &al.x; short* wlp = &wl.x;
                #pragma unroll
                for (int e = 0; e < 4; e++) {
                    union { float f; unsigned u; } ux, uy, mx, my, lx, ly;
                    ux.f = x[e]; uy.f = y[e];
                    ahp[e] = (short)(ux.u >> 16);
                    whp[e] = (short)(uy.u >> 16);
                    mx.u = ux.u & 0xFFFF0000u;   my.u = uy.u & 0xFFFF0000u;
                    lx.f = x[e] - mx.f;          ly.f = y[e] - my.f;
                    alp[e] = (short)(lx.u >> 16);
                    wlp[e] = (short)(ly.u >> 16);
                }
                *(short4*)(pool +            off) = ah;
                *(short4*)(pool +   TILE +   off) = wh;
                *(short4*)(pool + 2*TILE +   off) = al;
                *(short4*)(pool + 3*TILE +   off) = wl;
            } else {
                short4 sa, sw;
                sa.x = f2bf(x[0]); sa.y = f2bf(x[1]); sa.z = f2bf(x[2]); sa.w = f2bf(x[3]);
                sw.x = f2bf(y[0]); sw.y = f2bf(y[1]); sw.z = f2bf(y[2]); sw.w = f2bf(y[3]);
                *(short4*)(pool +        off) = sa;
                *(short4*)(pool + TILE + off) = sw;
            }
        }
    };

    f32x4 acc[4][4];
    #pragma unroll
    for (int i = 0; i < 4; i++)
        #pragma unroll
        for (int j = 0; j < 4; j++)
            acc[i][j] = (f32x4){0.f, 0.f, 0.f, 0.f};

    load_regs(0);
    for (int k0 = 0; k0 < K; k0 += 32) {
        __syncthreads();                       // prev readers done
        stage();
        if (k0 + 32 < K) load_regs(k0 + 32);   // prefetch overlaps MFMA phase
        __syncthreads();                       // tile visible
        bf16x8 a[4], b[4];
        #pragma unroll
        for (int i = 0; i < 4; i++)
            a[i] = *(const bf16x8*)(pool + (wm*64 + i*16 + fr) * RB + fq * 16);
        #pragma unroll
        for (int j = 0; j < 4; j++)
            b[j] = *(const bf16x8*)(pool + TILE + (wn*64 + j*16 + fr) * RB + fq * 16);
        if (SPLIT) {
            bf16x8 a2[4], b2[4];
            #pragma unroll
            for (int i = 0; i < 4; i++)
                a2[i] = *(const bf16x8*)(pool + 2*TILE + (wm*64 + i*16 + fr) * RB + fq * 16);
            #pragma unroll
            for (int j = 0; j < 4; j++)
                b2[j] = *(const bf16x8*)(pool + 3*TILE + (wn*64 + j*16 + fr) * RB + fq * 16);
            #pragma unroll
            for (int i = 0; i < 4; i++)
                #pragma unroll
                for (int j = 0; j < 4; j++) {
                    acc[i][j] = __builtin_amdgcn_mfma_f32_16x16x32_bf16(a[i],  b[j],  acc[i][j], 0, 0, 0);
                    acc[i][j] = __builtin_amdgcn_mfma_f32_16x16x32_bf16(a[i],  b2[j], acc[i][j], 0, 0, 0);
                    acc[i][j] = __builtin_amdgcn_mfma_f32_16x16x32_bf16(a2[i], b[j],  acc[i][j], 0, 0, 0);
                }
        } else {
            #pragma unroll
            for (int i = 0; i < 4; i++)
                #pragma unroll
                for (int j = 0; j < 4; j++)
                    acc[i][j] = __builtin_amdgcn_mfma_f32_16x16x32_bf16(a[i], b[j], acc[i][j], 0, 0, 0);
        }
    }

    if constexpr (!TRANS) {
        // C/D layout: col = lane&15, row = (lane>>4)*4 + reg
        #pragma unroll
        for (int i = 0; i < 4; i++)
            #pragma unroll
            for (int r = 0; r < 4; r++) {
                int m = m0 + wm * 64 + i * 16 + fq * 4 + r;
                size_t rowb = ((size_t)bz * LSEQ + m) * DM;
                #pragma unroll
                for (int j = 0; j < 4; j++) {
                    int n = n0 + wn * 64 + j * 16 + fr;
                    float val = acc[i][j][r];
                    if (bias)  val += bias[n];
                    if (resid) val += resid[rowb + n];
                    Y[rowb + n] = val;
                }
            }
    } else {
        // per-wave LDS transpose -> Y[b,n,m], m contiguous (coalesced)
        __syncthreads();
        float* sl = (float*)pool + wave * (64 * 17);
        #pragma unroll
        for (int i = 0; i < 4; i++) {
            #pragma unroll
            for (int j = 0; j < 4; j++) {
                int nn = j * 16 + fr;
                float bv = bias ? bias[n0 + wn * 64 + nn] : 0.f;
                #pragma unroll
                for (int r = 0; r < 4; r++)
                    sl[nn * 17 + fq * 4 + r] = acc[i][j][r] + bv;
            }
            const float* sr = sl + lane * 17;   // same-wave DS ordering
            int n = n0 + wn * 64 + lane;
            float* dst = Y + ((size_t)bz * DM + n) * LSEQ + m0 + wm * 64 + i * 16;
            #pragma unroll
            for (int g = 0; g < 4; g++) {
                float4 o = { sr[g*4+0], sr[g*4+1], sr[g*4+2], sr[g*4+3] };
                *(float4*)(dst + g * 4) = o;
            }
        }
    }
}

// ---------------------------------------------------------------------------
// Forward correlation spectrum (unchanged).
// ---------------------------------------------------------------------------
__global__ void __launch_bounds__(256)
fft_corr_k(const float* __restrict__ qt, const float* __restrict__ kt,
           float* __restrict__ S)
{
    __shared__ float zr[LSEQ], zi[LSEQ];
    __shared__ float twc[LSEQ/2], tws[LSEQ/2];
    const int cg  = blockIdx.x;
    const int b   = blockIdx.y;
    const int tid = (int)threadIdx.x;

    for (int j = tid; j < LSEQ/2; j += 256) {
        float ang = -2.0f * 3.14159265358979323846f * (float)j / (float)LSEQ;
        float s, c;
        sincosf(ang, &s, &c);
        twc[j] = c; tws[j] = s;
    }

    float Sr[16] = {}, Si[16] = {};

    for (int ci = 0; ci < 8; ci++) {
        const int ch = cg * 8 + ci;
        const float* qp = qt + ((size_t)b * DM + ch) * LSEQ;
        const float* kp = kt + ((size_t)b * DM + ch) * LSEQ;
        __syncthreads();
        for (int j = tid; j < LSEQ; j += 256) { zr[j] = qp[j]; zi[j] = kp[j]; }
        __syncthreads();
        for (int s = 11; s >= 0; s--) {
            int half = 1 << s;
            for (int bf = tid; bf < LSEQ/2; bf += 256) {
                int grp = bf >> s;
                int pos = bf & (half - 1);
                int i1  = (grp << (s + 1)) + pos;
                int i2  = i1 + half;
                int tdx = pos << (11 - s);
                float wc = twc[tdx], wsn = tws[tdx];
                float ur = zr[i1], ui = zi[i1];
                float vr = zr[i2], vi = zi[i2];
                zr[i1] = ur + vr;  zi[i1] = ui + vi;
                float dr = ur - vr, di = ui - vi;
                zr[i2] = wc * dr - wsn * di;
                zi[i2] = wc * di + wsn * dr;
            }
            __syncthreads();
        }
        #pragma unroll
        for (int j = 0; j < 16; j++) {
            int p  = tid + j * 256;
            int om = rev12(p);
            int pp = rev12((LSEQ - om) & (LSEQ - 1));
            float z1r = zr[p],  z1i = zi[p];
            float z2r = zr[pp], z2i = zi[pp];
            float Qr = 0.5f * (z1r + z2r);
            float Qi = 0.5f * (z1i - z2i);
            float Kr = 0.5f * (z1i + z2i);
            float Ki = 0.5f * (z2r - z1r);
            Sr[j] += Qr * Kr + Qi * Ki;
            Si[j] += Qi * Kr - Qr * Ki;
        }
    }
    float* Sb = S + (size_t)b * LSEQ * 2;
    #pragma unroll
    for (int j = 0; j < 16; j++) {
        int p = tid + j * 256;
        atomicAdd(&Sb[2*p],   Sr[j]);
        atomicAdd(&Sb[2*p+1], Si[j]);
    }
}

// ---------------------------------------------------------------------------
__global__ void __launch_bounds__(256)
ifft_topk_k(const float* __restrict__ S, float* __restrict__ wbuf, int* __restrict__ dbuf)
{
    __shared__ float zr[LSEQ], zi[LSEQ];
    __shared__ float twc[LSEQ/2], tws[LSEQ/2];
    __shared__ float rv[256];
    __shared__ int   ri[256];
    __shared__ float topv[8];
    __shared__ int   topi[8];
    const int b   = blockIdx.x;
    const int tid = (int)threadIdx.x;

    for (int j = tid; j < LSEQ/2; j += 256) {
        float ang = -2.0f * 3.14159265358979323846f * (float)j / (float)LSEQ;
        float s, c;
        sincosf(ang, &s, &c);
        twc[j] = c; tws[j] = s;
    }
    const float* Sb = S + (size_t)b * LSEQ * 2;
    for (int j = tid; j < LSEQ; j += 256) { zr[j] = Sb[2*j]; zi[j] = -Sb[2*j+1]; }
    __syncthreads();
    for (int s = 0; s < 12; s++) {
        int half = 1 << s;
        for (int bf = tid; bf < LSEQ/2; bf += 256) {
            int grp = bf >> s;
            int pos = bf & (half - 1);
            int i1  = (grp << (s + 1)) + pos;
            int i2  = i1 + half;
            int tdx = pos << (11 - s);
            float wc = twc[tdx], wsn = tws[tdx];
            float vr = zr[i2], vi = zi[i2];
            float tr = wc * vr - wsn * vi;
            float ti = wc * vi + wsn * vr;
            float ur = zr[i1], ui = zi[i1];
            zr[i1] = ur + tr;  zi[i1] = ui + ti;
            zr[i2] = ur - tr;  zi[i2] = ui - ti;
        }
        __syncthreads();
    }
    const float scale = 1.0f / ((float)LSEQ * (float)DM);
    for (int j = tid; j < LSEQ; j += 256) zr[j] *= scale;
    __syncthreads();

    for (int it = 0; it < 8; it++) {
        float best = -FLT_MAX; int bidx = 0;
        for (int j = tid; j < LSEQ; j += 256) {
            float vv = zr[j];
            if (vv > best) { best = vv; bidx = j; }
        }
        rv[tid] = best; ri[tid] = bidx;
        __syncthreads();
        for (int off = 128; off > 0; off >>= 1) {
            if (tid < off) {
                float ov = rv[tid+off]; int oi = ri[tid+off];
                if (ov > rv[tid] || (ov == rv[tid] && oi < ri[tid])) { rv[tid] = ov; ri[tid] = oi; }
            }
            __syncthreads();
        }
        if (tid == 0) {
            topv[it] = rv[0]; topi[it] = ri[0];
            zr[ri[0]] = -FLT_MAX;
        }
        __syncthreads();
    }
    if (tid == 0) {
        float m = topv[0];
        float e[8], sum = 0.f;
        #pragma unroll
        for (int i = 0; i < 8; i++) { e[i] = expf(topv[i] - m); sum += e[i]; }
        #pragma unroll
        for (int i = 0; i < 8; i++) { wbuf[b*8+i] = e[i] / sum; dbuf[b*8+i] = topi[i]; }
    }
}

// ---------------------------------------------------------------------------
__global__ void __launch_bounds__(256)
gather_k(const float* __restrict__ v, const float* __restrict__ wbuf,
         const int* __restrict__ dbuf, float* __restrict__ agg)
{
    const int l   = blockIdx.x;
    const int b   = blockIdx.y;
    const int tid = (int)threadIdx.x;
    __shared__ float w[8];
    __shared__ int   dd[8];
    if (tid < 8) { w[tid] = wbuf[b*8+tid]; dd[tid] = dbuf[b*8+tid]; }
    __syncthreads();
    const float* vb = v + (size_t)b * LSEQ * DM;
    int c = tid * 2;
    float2 acc = {0.f, 0.f};
    #pragma unroll
    for (int i = 0; i < 8; i++) {
        int src = (l + dd[i]) & (LSEQ - 1);
        float2 val = *(const float2*)(vb + (size_t)src * DM + c);
        acc.x += w[i] * val.x;
        acc.y += w[i] * val.y;
    }
    *(float2*)(agg + ((size_t)b * LSEQ + l) * DM + c) = acc;
}

// ---------------------------------------------------------------------------
extern "C" void kernel_launch(void* const* d_in, const int* in_sizes, int n_in,
                              void* d_out, int out_size, void* d_ws, size_t ws_size,
                              hipStream_t stream)
{
    const float* x_s = (const float*)d_in[0];
    const float* x_w = (const float*)d_in[1];
    const float* Wq  = (const float*)d_in[2];
    const float* bq  = (const float*)d_in[3];
    const float* Wk  = (const float*)d_in[4];
    const float* bk  = (const float*)d_in[5];
    const float* Wv  = (const float*)d_in[6];
    const float* bv  = (const float*)d_in[7];
    const float* Wo  = (const float*)d_in[8];
    const float* bo  = (const float*)d_in[9];
    const float* Wc  = (const float*)d_in[10];   // (out=512, in=512, k=3)

    float* out_s = (float*)d_out;                        // x_s_out [B,L,D]
    float* out_w = out_s + (size_t)NB * LSEQ * DM;       // x_w_out [B,L,D]

    const size_t NBLD = (size_t)NB * LSEQ * DM;          // 16,777,216 floats
    const size_t SMALL = (size_t)NB * LSEQ * 2 + 4096 + (size_t)3 * DM * DM; // S + pad + wt
    float* ws = (float*)d_ws;
    float* qt = ws;                  // [B,D,L] q^T (f32)
    float* kt = ws + NBLD;           // [B,D,L] k^T (f32)
    const size_t need3 = (3 * NBLD + SMALL) * sizeof(float);
    float* vbuf = (ws_size >= need3) ? (ws + 2 * NBLD) : out_w;   // v dead before conv writes out_w
    float* base = (ws_size >= need3) ? (ws + 3 * NBLD) : (ws + 2 * NBLD);
    float* Sbuf = base;
    float* wbuf = Sbuf + (size_t)NB * LSEQ * 2;
    int*   dbuf = (int*)(wbuf + NB * 8);
    float* wt   = base + (size_t)NB * LSEQ * 2 + 4096;   // [3][512][512]
    float* agg  = qt;                // reuse: qt dead after fft_corr_k

    dim3 mgrid(LSEQ / 128, DM / 128, NB);

    wconv_tr_k<<<dim3(1024), 256, 0, stream>>>(Wc, wt);

    // q^T, k^T: split-precision MFMA (selection-critical); v: plain bf16 MFMA
    mm_k<1,1,0><<<mgrid, 256, 0, stream>>>(x_w, Wq, bq, nullptr, qt);
    mm_k<1,1,0><<<mgrid, 256, 0, stream>>>(x_s, Wk, bk, nullptr, kt);
    mm_k<0,0,0><<<mgrid, 256, 0, stream>>>(x_s, Wv, bv, nullptr, vbuf);

    hipMemsetAsync(Sbuf, 0, (size_t)NB * LSEQ * 2 * sizeof(float), stream);

    fft_corr_k <<<dim3(64, NB),   256, 0, stream>>>(qt, kt, Sbuf);
    ifft_topk_k<<<dim3(NB),       256, 0, stream>>>(Sbuf, wbuf, dbuf);
    gather_k   <<<dim3(LSEQ, NB), 256, 0, stream>>>(vbuf, wbuf, dbuf, agg);

    // x_s_out = x_s + agg@Wo.T + bo
    mm_k<0,0,0><<<mgrid, 256, 0, stream>>>(agg, Wo, bo, x_s, out_s);

    // x_w_out = circular conv1d, fused as one K=1536 GEMM (pre-transposed W)
    mm_k<0,0,1><<<mgrid, 256, 0, stream>>>(x_w, wt, nullptr, nullptr, out_w);
}